// Round 14
// baseline (116.252 us; speedup 1.0000x reference)
//
#include <hip/hip_runtime.h>
#include <hip/hip_bf16.h>

#define M_TOK 2048
#define KDIM  4096
#define NDIM  4096
#define BM    256
#define BN    256
#define BK    64
#define BUF   32768                // ushorts per buffer: A 16K + B 16K = 64 KB

typedef __bf16 bf16x8 __attribute__((ext_vector_type(8)));
typedef float  f32x4  __attribute__((ext_vector_type(4)));
typedef short  short8 __attribute__((ext_vector_type(8)));

__device__ __forceinline__ ushort f2bf(float f) {
    union { float f; unsigned u; } v; v.f = f;
    unsigned r = (v.u + 0x7fffu + ((v.u >> 16) & 1u)) >> 16;
    return (ushort)r;
}

__device__ __forceinline__ void gload16(const ushort* g, ushort* l) {
    __builtin_amdgcn_global_load_lds(
        (const __attribute__((address_space(1))) void*)g,
        (__attribute__((address_space(3))) void*)l, 16, 0, 0);
}

// ---------------- kernel 1: cast x -> bf16  AND  build W3 row-major ----------------
__global__ __launch_bounds__(256) void k_prep(const float* __restrict__ x,
                                              ushort* __restrict__ xb,
                                              const float* __restrict__ g0,
                                              const float* __restrict__ g1,
                                              const float* __restrict__ alpha,
                                              const float* __restrict__ pds,
                                              const int* __restrict__ iperm,
                                              const int* __restrict__ oinv,
                                              ushort* __restrict__ W3) {
    __shared__ float  G0s[1024];   // [j0][r]
    __shared__ float  G1s[1024];   // [r][j1]
    __shared__ ushort rowb[4096];
    const int b = blockIdx.x;
    if (b < 4096) {
        const int i = (b * 256 + threadIdx.x) * 8;
        float4 a = *reinterpret_cast<const float4*>(x + i);
        float4 c = *reinterpret_cast<const float4*>(x + i + 4);
        short8 o;
        o[0] = (short)f2bf(a.x); o[1] = (short)f2bf(a.y);
        o[2] = (short)f2bf(a.z); o[3] = (short)f2bf(a.w);
        o[4] = (short)f2bf(c.x); o[5] = (short)f2bf(c.y);
        o[6] = (short)f2bf(c.z); o[7] = (short)f2bf(c.w);
        *reinterpret_cast<short8*>(xb + i) = o;
        return;
    }
    const int o  = b - 4096;
    const int op = oinv[o];
    const int i0 = op >> 6, i1 = op & 63;
    const float sc = alpha[0] * pds[op];

    for (int idx = threadIdx.x; idx < 1024; idx += 256) {
        G0s[idx] = g0[i0 * 1024 + idx];
        G1s[idx] = g1[(idx >> 6) * 4096 + i1 * 64 + (idx & 63)];
    }
    __syncthreads();

    float g1c[16];
#pragma unroll
    for (int r = 0; r < 16; ++r) g1c[r] = G1s[r * 64 + (threadIdx.x & 63)];

#pragma unroll 4
    for (int s = 0; s < 16; ++s) {
        const int jp = threadIdx.x + s * 256;
        const int j0 = jp >> 6;
        const float4 q0 = *reinterpret_cast<const float4*>(&G0s[j0 * 16]);
        const float4 q1 = *reinterpret_cast<const float4*>(&G0s[j0 * 16 + 4]);
        const float4 q2 = *reinterpret_cast<const float4*>(&G0s[j0 * 16 + 8]);
        const float4 q3 = *reinterpret_cast<const float4*>(&G0s[j0 * 16 + 12]);
        float v = 0.f;
        v = fmaf(q0.x, g1c[0], v);  v = fmaf(q0.y, g1c[1], v);
        v = fmaf(q0.z, g1c[2], v);  v = fmaf(q0.w, g1c[3], v);
        v = fmaf(q1.x, g1c[4], v);  v = fmaf(q1.y, g1c[5], v);
        v = fmaf(q1.z, g1c[6], v);  v = fmaf(q1.w, g1c[7], v);
        v = fmaf(q2.x, g1c[8], v);  v = fmaf(q2.y, g1c[9], v);
        v = fmaf(q2.z, g1c[10], v); v = fmaf(q2.w, g1c[11], v);
        v = fmaf(q3.x, g1c[12], v); v = fmaf(q3.y, g1c[13], v);
        v = fmaf(q3.z, g1c[14], v); v = fmaf(q3.w, g1c[15], v);
        rowb[iperm[jp]] = f2bf(v * sc);
    }
    __syncthreads();
#pragma unroll
    for (int u = 0; u < 2; ++u) {
        const int t = threadIdx.x + u * 256;
        *reinterpret_cast<short8*>(W3 + (size_t)o * 4096 + t * 8) =
            *reinterpret_cast<const short8*>(rowb + t * 8);
    }
}

// ---------------- kernel 2: C = A @ B^T (+ bias)  [balanced-phase, split-K] ------
// 256x256 tile, BK=64, 512 thr = 8 waves (2M x 4N), wave tile 128x64.
// 2-buffer LDS (128KB). Phases per K-tile: (mh,kk) quadrants with reads
// 8/4/8/4 per wave (bf regs held across kk-pair). Staging units = 64-row
// quarters (1 gload16/thread); calendar {ph1:B01(t+1), ph2:B23(t+1),
// ph3:A02(t+1), ph4:A13(t+2)} -> every unit lands >=4 phases before first
// read; ONE vmcnt(2) per tile (before the tile-end barrier).
__global__ __launch_bounds__(512, 2)
void k_gemm(const ushort* __restrict__ A, const ushort* __restrict__ Bw,
            const float* __restrict__ bias, float* __restrict__ Cout,
            float* __restrict__ P1, int ksplit) {
    __shared__ __align__(16) ushort lds[2 * BUF];   // 128 KB
    const int tid  = threadIdx.x;
    const int lane = tid & 63;
    const int w    = tid >> 6;   // 0..7
    const int wm   = w >> 2;     // 0..1
    const int wn   = w & 3;      // 0..3

    int half, r;
    if (ksplit == 2) { half = blockIdx.x >> 7; r = blockIdx.x & 127; }
    else             { half = 0;               r = blockIdx.x; }
    const int ntk   = (ksplit == 2) ? 32 : 64;
    const int kbase = half * 2048;
    // XCD map over 128: 8x16 grid; kz pairs (bid, bid+128) share XCD slot
    const int xcd = r & 7, li = r >> 3;       // li 0..15
    const int by = li >> 1;                   // 0..7
    const int bx = xcd * 2 + (li & 1);        // 0..15
    const long brow = (long)by * BM, bcol = (long)bx * BN;

    float* const dst = half ? P1 : Cout;

    // ---- staging: unit = 64-row quarter (8KB = 1 gload16/thread).
    // thread t -> row t>>3, LDS slot t&7, global slot pre-swizzled ^ (row&7)
    const int rowt = tid >> 3;
    const int scol = ((tid & 7) ^ (rowt & 7)) << 3;
    const ushort* gA0 = A  + (size_t)(brow + rowt) * KDIM + scol;
    const ushort* gB0 = Bw + (size_t)(bcol + rowt) * KDIM + scol;
    const int wub = (tid & ~63) * 8;

    auto stA = [&](int bufo, int t, int q) {
        gload16(gA0 + (size_t)(q * 64) * KDIM + kbase + t * BK,
                (ushort*)lds + bufo + q * 4096 + wub);
    };
    auto stB = [&](int bufo, int t, int q) {
        gload16(gB0 + (size_t)(q * 64) * KDIM + kbase + t * BK,
                (ushort*)lds + bufo + 16384 + q * 4096 + wub);
    };

    // ---- fragment reads (proven zero-conflict, 128B rows)
    const int lr = lane & 15;
    int colswz[2];
#pragma unroll
    for (int kk = 0; kk < 2; ++kk)
        colswz[kk] = ((kk * 4 + (lane >> 4)) ^ (lane & 7)) * 8;
    const int rA0 = (wm * 128 + lr) * 64;           // + mh*4096 + m*1024
    const int rB  = 16384 + (wn * 64 + lr) * 64;    // + n*1024

    f32x4  acc[8][4] = {};
    bf16x8 af[4], bf[4];

#define BARRIER do { asm volatile("" ::: "memory"); \
                     __builtin_amdgcn_s_barrier();  \
                     asm volatile("" ::: "memory"); } while (0)

    // PHASE: read A-quarter frags (4) [+ B frags (4) if RB], stage, barrier,
    //        16 MFMA, optional wait, barrier.
#define PHASE(MH, KK, RB, STAGE_STMT, WAIT_STMT)                               \
    do {                                                                       \
        _Pragma("unroll") for (int m = 0; m < 4; ++m)                          \
            af[m] = *reinterpret_cast<const bf16x8*>(                          \
                lds + bufo + rA0 + (MH) * 4096 + m * 1024 + colswz[KK]);       \
        if (RB) {                                                              \
            _Pragma("unroll") for (int n = 0; n < 4; ++n)                      \
                bf[n] = *reinterpret_cast<const bf16x8*>(                      \
                    lds + bufo + rB + n * 1024 + colswz[KK]);                  \
        }                                                                      \
        STAGE_STMT;                                                            \
        BARRIER;                                                               \
        __builtin_amdgcn_s_setprio(1);                                         \
        _Pragma("unroll") for (int m = 0; m < 4; ++m)                          \
            _Pragma("unroll") for (int n = 0; n < 4; ++n)                      \
                acc[(MH) * 4 + m][n] = __builtin_amdgcn_mfma_f32_16x16x32_bf16(\
                    af[m], bf[n], acc[(MH) * 4 + m][n], 0, 0, 0);              \
        __builtin_amdgcn_s_setprio(0);                                         \
        __builtin_amdgcn_sched_barrier(0);                                     \
        WAIT_STMT;                                                             \
        BARRIER;                                                               \
    } while (0)

#define VM2 asm volatile("s_waitcnt vmcnt(2)" ::: "memory")
#define VM0 asm volatile("s_waitcnt vmcnt(0)" ::: "memory")

    // prologue: tile0's 8 units (A13 first = steady order) + A13(1) -> buf1
    stA(0, 0, 1); stA(0, 0, 3);
    stB(0, 0, 0); stB(0, 0, 1); stB(0, 0, 2); stB(0, 0, 3);
    stA(0, 0, 0); stA(0, 0, 2);
    if (ntk > 1) { stA(BUF, 1, 1); stA(BUF, 1, 3); }
    VM2;   // tile0 landed; A13(1) may remain in flight
    BARRIER;

    for (int t = 0; t < ntk; ++t) {
        const int bufo = (t & 1) * BUF;
        const int nxto = bufo ^ BUF;
        const bool s1 = (t + 1 < ntk), s2 = (t + 2 < ntk);
        // ph1 (mh0,kk0): reads A-q(wm*2) kk0 + B kk0 | stage B01(t+1)
        PHASE(0, 0, 1, { if (s1) { stB(nxto, t + 1, 0); stB(nxto, t + 1, 1); } }, );
        // ph2 (mh1,kk0): reads A-q(wm*2+1) kk0        | stage B23(t+1)
        PHASE(1, 0, 0, { if (s1) { stB(nxto, t + 1, 2); stB(nxto, t + 1, 3); } }, );
        // ph3 (mh1,kk1): reads A kk1 + B kk1          | stage A02(t+1)
        PHASE(1, 1, 1, { if (s1) { stA(nxto, t + 1, 0); stA(nxto, t + 1, 2); } }, );
        // ph4 (mh0,kk1): reads A kk1                  | stage A13(t+2) -> bufo
        if (t < ntk - 2) {
            PHASE(0, 1, 0, { stA(bufo, t + 2, 1); stA(bufo, t + 2, 3); }, VM2);
        } else if (t == ntk - 2) {
            PHASE(0, 1, 0, {}, VM0);
        } else {
            PHASE(0, 1, 0, {}, );
        }
    }
#undef PHASE
#undef VM2
#undef VM0
#undef BARRIER

    // ---- epilogue: C/D col = lane&15, row = (lane>>4)*4 + v
    const int orow = (lane >> 4) * 4;
    float bv[4];
#pragma unroll
    for (int n = 0; n < 4; ++n)
        bv[n] = half ? 0.f : bias[bcol + wn * 64 + n * 16 + lr];
#pragma unroll
    for (int ma = 0; ma < 8; ++ma) {
        const int roff = (ma >> 2) * 64 + (ma & 3) * 16;   // mh*64 + m*16
#pragma unroll
        for (int v = 0; v < 4; ++v) {
            const long grow = brow + wm * 128 + roff + orow + v;
            float* cp = dst + grow * NDIM + bcol + wn * 64 + lr;
#pragma unroll
            for (int n = 0; n < 4; ++n)
                cp[n * 16] = acc[ma][n][v] + bv[n];
        }
    }
}

// ---------------- kernel 3: out += P1 ----------------
__global__ __launch_bounds__(256) void k_red(float* __restrict__ out,
                                             const float* __restrict__ p1) {
    const int i = (blockIdx.x * 256 + threadIdx.x) * 4;
    float4 a = *reinterpret_cast<const float4*>(out + i);
    const float4 b = *reinterpret_cast<const float4*>(p1 + i);
    a.x += b.x; a.y += b.y; a.z += b.z; a.w += b.w;
    *reinterpret_cast<float4*>(out + i) = a;
}

extern "C" void kernel_launch(void* const* d_in, const int* in_sizes, int n_in,
                              void* d_out, int out_size, void* d_ws, size_t ws_size,
                              hipStream_t stream) {
    const float* x     = (const float*)d_in[0];
    const float* g0    = (const float*)d_in[1];
    const float* g1    = (const float*)d_in[2];
    const float* alpha = (const float*)d_in[3];
    const float* pds   = (const float*)d_in[4];
    const float* bias  = (const float*)d_in[5];
    const int*   iperm = (const int*)d_in[6];
    const int*   oinv  = (const int*)d_in[7];
    float* out = (float*)d_out;

    ushort* W3 = (ushort*)d_ws;                         // 32MB bf16 W3
    ushort* Xb = (ushort*)d_ws + (size_t)NDIM * KDIM;   // 16MB bf16 A
    const bool split = ws_size >= (size_t)80 * 1024 * 1024;
    float* P1 = split ? (float*)((char*)d_ws + (size_t)48 * 1024 * 1024)
                      : (float*)d_ws;

    hipLaunchKernelGGL(k_prep, dim3(8192), dim3(256), 0, stream,
                       x, Xb, g0, g1, alpha, pds, iperm, oinv, W3);
    if (split) {
        hipLaunchKernelGGL(k_gemm, dim3(256), dim3(512), 0, stream,
                           Xb, W3, bias, out, P1, 2);
        hipLaunchKernelGGL(k_red, dim3((M_TOK * NDIM) / (256 * 4)), dim3(256), 0,
                           stream, out, P1);
    } else {
        hipLaunchKernelGGL(k_gemm, dim3(128), dim3(512), 0, stream,
                           Xb, W3, bias, out, P1, 1);
    }
}

// Round 15
// 98.119 us; speedup vs baseline: 1.1848x; 1.1848x over previous
//
#include <hip/hip_runtime.h>
#include <hip/hip_bf16.h>

#define M_TOK 2048
#define KDIM  4096
#define NDIM  4096
#define BM    128
#define BN    256
#define BK    64
#define NT    (KDIM / BK)          // 64 K-tiles
#define ABUFU 8192                 // ushorts per A buffer (128x64 bf16 = 16 KB)
#define BBUFU 16384                // ushorts per B buffer (256x64 bf16 = 32 KB)
#define BBASE 24576                // B region starts after 3 A buffers

typedef __bf16 bf16x8 __attribute__((ext_vector_type(8)));
typedef float  f32x4  __attribute__((ext_vector_type(4)));
typedef short  short8 __attribute__((ext_vector_type(8)));

__device__ __forceinline__ ushort f2bf(float f) {
    union { float f; unsigned u; } v; v.f = f;
    unsigned r = (v.u + 0x7fffu + ((v.u >> 16) & 1u)) >> 16;
    return (ushort)r;
}

__device__ __forceinline__ void gload16(const ushort* g, ushort* l) {
    __builtin_amdgcn_global_load_lds(
        (const __attribute__((address_space(1))) void*)g,
        (__attribute__((address_space(3))) void*)l, 16, 0, 0);
}

// ---------------- kernel 1: cast x -> bf16  AND  build W3 row-major ----------------
__global__ __launch_bounds__(256) void k_prep(const float* __restrict__ x,
                                              ushort* __restrict__ xb,
                                              const float* __restrict__ g0,
                                              const float* __restrict__ g1,
                                              const float* __restrict__ alpha,
                                              const float* __restrict__ pds,
                                              const int* __restrict__ iperm,
                                              const int* __restrict__ oinv,
                                              ushort* __restrict__ W3) {
    __shared__ float  G0s[1024];   // [j0][r]
    __shared__ float  G1s[1024];   // [r][j1]
    __shared__ ushort rowb[4096];
    const int b = blockIdx.x;
    if (b < 4096) {
        const int i = (b * 256 + threadIdx.x) * 8;
        float4 a = *reinterpret_cast<const float4*>(x + i);
        float4 c = *reinterpret_cast<const float4*>(x + i + 4);
        short8 o;
        o[0] = (short)f2bf(a.x); o[1] = (short)f2bf(a.y);
        o[2] = (short)f2bf(a.z); o[3] = (short)f2bf(a.w);
        o[4] = (short)f2bf(c.x); o[5] = (short)f2bf(c.y);
        o[6] = (short)f2bf(c.z); o[7] = (short)f2bf(c.w);
        *reinterpret_cast<short8*>(xb + i) = o;
        return;
    }
    const int o  = b - 4096;
    const int op = oinv[o];
    const int i0 = op >> 6, i1 = op & 63;
    const float sc = alpha[0] * pds[op];

    for (int idx = threadIdx.x; idx < 1024; idx += 256) {
        G0s[idx] = g0[i0 * 1024 + idx];
        G1s[idx] = g1[(idx >> 6) * 4096 + i1 * 64 + (idx & 63)];
    }
    __syncthreads();

    float g1c[16];
#pragma unroll
    for (int r = 0; r < 16; ++r) g1c[r] = G1s[r * 64 + (threadIdx.x & 63)];

#pragma unroll 4
    for (int s = 0; s < 16; ++s) {
        const int jp = threadIdx.x + s * 256;
        const int j0 = jp >> 6;
        const float4 q0 = *reinterpret_cast<const float4*>(&G0s[j0 * 16]);
        const float4 q1 = *reinterpret_cast<const float4*>(&G0s[j0 * 16 + 4]);
        const float4 q2 = *reinterpret_cast<const float4*>(&G0s[j0 * 16 + 8]);
        const float4 q3 = *reinterpret_cast<const float4*>(&G0s[j0 * 16 + 12]);
        float v = 0.f;
        v = fmaf(q0.x, g1c[0], v);  v = fmaf(q0.y, g1c[1], v);
        v = fmaf(q0.z, g1c[2], v);  v = fmaf(q0.w, g1c[3], v);
        v = fmaf(q1.x, g1c[4], v);  v = fmaf(q1.y, g1c[5], v);
        v = fmaf(q1.z, g1c[6], v);  v = fmaf(q1.w, g1c[7], v);
        v = fmaf(q2.x, g1c[8], v);  v = fmaf(q2.y, g1c[9], v);
        v = fmaf(q2.z, g1c[10], v); v = fmaf(q2.w, g1c[11], v);
        v = fmaf(q3.x, g1c[12], v); v = fmaf(q3.y, g1c[13], v);
        v = fmaf(q3.z, g1c[14], v); v = fmaf(q3.w, g1c[15], v);
        rowb[iperm[jp]] = f2bf(v * sc);
    }
    __syncthreads();
#pragma unroll
    for (int u = 0; u < 2; ++u) {
        const int t = threadIdx.x + u * 256;
        *reinterpret_cast<short8*>(W3 + (size_t)o * 4096 + t * 8) =
            *reinterpret_cast<const short8*>(rowb + t * 8);
    }
}

// ---------------- kernel 2: C = A @ B^T + bias ----------------
// BM=128 x BN=256, 512 thr = 8 waves (2M x 4N, wave tile 64x64), 16x16x32.
// Triple-buffered A (3x16KB, mh-partitioned units) + triple-buffered B
// (3x32KB) = 144KB LDS. 4 single-barrier phases per 2-tile iter, split by
// m-half; B frags held in regs across a tile's phases. 3 gloads/phase;
// every unit staged >=4 phases before first read; vmcnt(6) twice/iter
// (never 0 until the final iter). Proven zero-conflict swizzle. Grid 256.
__global__ __launch_bounds__(512, 1)
void k_gemm(const ushort* __restrict__ A, const ushort* __restrict__ Bw,
            const float* __restrict__ bias, float* __restrict__ C) {
    __shared__ __align__(16) ushort lds[BBASE + 3 * BBUFU];   // 144 KB
    const int tid  = threadIdx.x;
    const int lane = tid & 63;
    const int w    = tid >> 6;   // 0..7
    const int wm   = w >> 2;     // 0..1 (M)
    const int wn   = w & 3;      // 0..3 (N)

    // XCD map: 256 blocks = 16(by) x 16(bx); XCD owns 2 bx x 16 by
    const int bid = blockIdx.x;
    const int xcd = bid & 7, li = bid >> 3;   // li 0..31
    const int by = li >> 1;                   // 0..15
    const int bx = xcd * 2 + (li & 1);        // 0..15
    const long brow = (long)by * BM, bcol = (long)bx * BN;

    // ---- staging: unit = 64 "rows" of 64 k (8KB, 1 gload16/thread).
    // A units are mh-partitioned: unit u holds global rows u*32 + {0..31, 64..95}
    // so each unit dies at its phase boundary. Thread t -> in-unit index t>>3,
    // LDS slot t&7; global slot pre-swizzled ^ (idx&7).
    const int idx  = tid >> 3;                 // 0..63
    const int scol = ((tid & 7) ^ (idx & 7)) << 3;
    const int arow = (idx & 31) + (idx >> 5) * 64;   // + u*32
    const ushort* gA0 = A  + (size_t)(brow + arow) * KDIM + scol;
    const ushort* gB0 = Bw + (size_t)(bcol + idx) * KDIM + scol;
    const int wub = (tid & ~63) * 8;

    auto stA = [&](int abufo, int t, int u) {
        gload16(gA0 + (size_t)(u * 32) * KDIM + t * BK,
                (ushort*)lds + abufo + u * 4096 + wub);
    };
    auto stB = [&](int bbufo, int t, int q) {
        gload16(gB0 + (size_t)(q * 64) * KDIM + t * BK,
                (ushort*)lds + BBASE + bbufo + q * 4096 + wub);
    };

    // ---- fragment reads (proven zero-conflict pattern, 128B rows)
    const int lr = lane & 15;
    int colswz[2];
#pragma unroll
    for (int kk = 0; kk < 2; ++kk)
        colswz[kk] = ((kk * 4 + (lane >> 4)) ^ (lane & 7)) * 8;
    const int rAu = (wm * 32 + lr) * 64;       // + mi*1024, within A unit
    const int rBn = lr * 64;                   // + n*1024, within B unit wn

    f32x4  acc[4][4] = {};
    bf16x8 bf[4][2];   // persists across a tile's two phases

#define BARRIER do { asm volatile("" ::: "memory"); \
                     __builtin_amdgcn_s_barrier();  \
                     asm volatile("" ::: "memory"); } while (0)

    // Single-barrier phase: reads -> stages -> MFMA -> [wait] -> barrier.
#define PH(MH, ABUFO, BBUFO, READB, STAGES, WAITS)                             \
    do {                                                                       \
        bf16x8 af[2][2];                                                       \
        _Pragma("unroll") for (int mi = 0; mi < 2; ++mi)                       \
            _Pragma("unroll") for (int kk = 0; kk < 2; ++kk)                   \
                af[mi][kk] = *reinterpret_cast<const bf16x8*>(                 \
                    lds + (ABUFO) + (MH) * 4096 + rAu + mi * 1024 + colswz[kk]);\
        if (READB) {                                                           \
            _Pragma("unroll") for (int n = 0; n < 4; ++n)                      \
                _Pragma("unroll") for (int kk = 0; kk < 2; ++kk)               \
                    bf[n][kk] = *reinterpret_cast<const bf16x8*>(              \
                        lds + BBASE + (BBUFO) + wn * 4096 + rBn + n * 1024     \
                        + colswz[kk]);                                         \
        }                                                                      \
        STAGES;                                                                \
        __builtin_amdgcn_s_setprio(1);                                         \
        _Pragma("unroll") for (int kk = 0; kk < 2; ++kk)                       \
            _Pragma("unroll") for (int mi = 0; mi < 2; ++mi)                   \
                _Pragma("unroll") for (int n = 0; n < 4; ++n)                  \
                    acc[(MH) * 2 + mi][n] =                                    \
                        __builtin_amdgcn_mfma_f32_16x16x32_bf16(               \
                            af[mi][kk], bf[n][kk], acc[(MH) * 2 + mi][n],      \
                            0, 0, 0);                                          \
        __builtin_amdgcn_s_setprio(0);                                         \
        WAITS;                                                                 \
        BARRIER;                                                               \
    } while (0)

#define VM6 asm volatile("s_waitcnt vmcnt(6)" ::: "memory")
#define VM0 asm volatile("s_waitcnt vmcnt(0)" ::: "memory")

    // buffer rotations (ushort offsets within each region)
    int aE = 0, aO = ABUFU, aS = 2 * ABUFU;
    int bE = 0, bO = BBUFU, bS = 2 * BBUFU;

    // prologue: tile0 -> E bufs, tile1 -> O bufs (12 loads); wait tile0
    stA(aE, 0, 0); stA(aE, 0, 1);
    stB(bE, 0, 0); stB(bE, 0, 1); stB(bE, 0, 2); stB(bE, 0, 3);
    stA(aO, 1, 0); stA(aO, 1, 1);
    stB(bO, 1, 0); stB(bO, 1, 1); stB(bO, 1, 2); stB(bO, 1, 3);
    VM6;
    BARRIER;

    for (int it = 0; it < NT / 2; ++it) {
        const int e = 2 * it;
        const bool st = (it + 1 < NT / 2);
        // ph1: tile e mh0 (12 reads) | stage B(e+2)u0,u1 + A(e+2)u0 -> S bufs
        PH(0, aE, bE, 1,
           { if (st) { stB(bS, e + 2, 0); stB(bS, e + 2, 1); stA(aS, e + 2, 0); } }, );
        // ph2: tile e mh1 (4 reads) | stage B(e+2)u2,u3 + A(e+2)u1 -> S
        //      wait: tile o (=e+1) landed (counted 6; drain only on last iter)
        PH(1, aE, bE, 0,
           { if (st) { stB(bS, e + 2, 2); stB(bS, e + 2, 3); stA(aS, e + 2, 1); } },
           { if (st) VM6; else VM0; });
        // ph3: tile o mh0 (12 reads) | stage B(e+3)u0,u1 + A(e+3)u0 -> E bufs
        //      (E dead since ph2-end barrier)
        PH(0, aO, bO, 1,
           { if (st) { stB(bE, e + 3, 0); stB(bE, e + 3, 1); stA(aE, e + 3, 0); } }, );
        // ph4: tile o mh1 (4 reads) | stage B(e+3)u2,u3 + A(e+3)u1 -> E
        //      wait: tile e+2 landed (counted 6)
        PH(1, aO, bO, 0,
           { if (st) { stB(bE, e + 3, 2); stB(bE, e + 3, 3); stA(aE, e + 3, 1); } },
           { if (st) VM6; });
        // rotate (E,O,S) <- (S,E,O)
        int t;
        t = aE; aE = aS; aS = aO; aO = t;
        t = bE; bE = bS; bS = bO; bO = t;
    }
#undef PH
#undef VM6
#undef VM0
#undef BARRIER

    // ---- epilogue: C/D col = lane&15, row = (lane>>4)*4 + v
    const int orow = (lane >> 4) * 4;
    float bv[4];
#pragma unroll
    for (int n = 0; n < 4; ++n) bv[n] = bias[bcol + wn * 64 + n * 16 + lr];
#pragma unroll
    for (int m = 0; m < 4; ++m) {
#pragma unroll
        for (int v = 0; v < 4; ++v) {
            const long grow = brow + wm * 64 + m * 16 + orow + v;
            float* cp = C + grow * NDIM + bcol + wn * 64 + lr;
#pragma unroll
            for (int n = 0; n < 4; ++n)
                cp[n * 16] = acc[m][n][v] + bv[n];
        }
    }
}

extern "C" void kernel_launch(void* const* d_in, const int* in_sizes, int n_in,
                              void* d_out, int out_size, void* d_ws, size_t ws_size,
                              hipStream_t stream) {
    const float* x     = (const float*)d_in[0];
    const float* g0    = (const float*)d_in[1];
    const float* g1    = (const float*)d_in[2];
    const float* alpha = (const float*)d_in[3];
    const float* pds   = (const float*)d_in[4];
    const float* bias  = (const float*)d_in[5];
    const int*   iperm = (const int*)d_in[6];
    const int*   oinv  = (const int*)d_in[7];
    float* out = (float*)d_out;

    ushort* W3 = (ushort*)d_ws;                         // 32MB bf16 W3
    ushort* Xb = (ushort*)d_ws + (size_t)NDIM * KDIM;   // 16MB bf16 A

    hipLaunchKernelGGL(k_prep, dim3(8192), dim3(256), 0, stream,
                       x, Xb, g0, g1, alpha, pds, iperm, oinv, W3);
    hipLaunchKernelGGL(k_gemm, dim3((M_TOK / BM) * (NDIM / BN)), dim3(512), 0, stream,
                       Xb, W3, bias, out);
}